// Round 5
// baseline (468.540 us; speedup 1.0000x reference)
//
#include <hip/hip_runtime.h>
#include <hip/hip_fp16.h>
#include <math.h>

// LiquidNet2: B=1024, I=128, S=512, UNFOLDS=6, out v[B,S] fp32.
//
// Sigmoid via 32-way bank-replicated LDS table with f16 linear interpolation:
//   s = 1/(1+2^t),  t = A*v + C,  A=-sigma*log2e, C=sigma*mu*log2e
//   f = fma(A*SCALE, v, C*SCALE + TBL_N/2);  f = med3(f, 0, TBL_N-1)
//   k = floor(f), frac = fract(f)
//   entry(k, rep) at byte k*128 + rep*4, rep = lane&31 -> bank = lane&31 for
//   ANY k  => conflict-free gather by construction (2-way lane alias is free).
//   entry = half2(value = s(t_k), slope = s(t_{k+1}) - s(t_k))
//   s = v_fma_mix_f32(slope_f16, frac_f32, value_f16)   (one instr interp)
// Params in grouped 48B records per (group-of-4-i, j):
//   {float2 ac[4] (A', C')} + {half2 wh[4] (Wn=W*erev, Wp=W)}
// Accumulation via v_fma_mix_f32 (f16 W operand, f32 accumulate).

#define B_TOT 1024
#define I_DIM 128
#define S_DIM 512
#define UNFOLDS 6
#define BT 4
#define TBL_N 1024
#define NREP 32
#define T_MAX 14.0f

struct __align__(16) Rec {
    float2   ac[4];     // (A', C') for 4 consecutive i
    unsigned wh[4];     // half2(Wn, Wp)
};

__global__ __launch_bounds__(256) void prep_kernel(
    const float* __restrict__ sens_mu, const float* __restrict__ sens_sigma,
    const float* __restrict__ sens_W, const float* __restrict__ sens_erev,
    const float* __restrict__ mu, const float* __restrict__ sigma,
    const float* __restrict__ W, const float* __restrict__ erev,
    Rec* __restrict__ recG, Rec* __restrict__ sensG)
{
    const float L2E   = 1.4426950408889634f;
    const float SCALE = (float)TBL_N / (2.0f * T_MAX);
    const float OFF   = (float)(TBL_N / 2);          // left-edge indexing (interp)
    int idx = blockIdx.x * 256 + threadIdx.x;
    int j = idx & (S_DIM - 1);
    int g = idx >> 9;
    if (g < S_DIM / 4) {
        Rec r;
        #pragma unroll
        for (int u = 0; u < 4; ++u) {
            int o = (g * 4 + u) * S_DIM + j;
            float sg = sigma[o], m = mu[o], w = W[o], er = erev[o];
            r.ac[u] = make_float2(-sg * L2E * SCALE, sg * m * L2E * SCALE + OFF);
            __half2 h = __floats2half2_rn(w * er, w);
            r.wh[u] = __builtin_bit_cast(unsigned, h);
        }
        recG[g * S_DIM + j] = r;
    }
    if (g < I_DIM / 4) {
        Rec r;
        #pragma unroll
        for (int u = 0; u < 4; ++u) {
            int o = (g * 4 + u) * S_DIM + j;
            float sg = sens_sigma[o], m = sens_mu[o], w = sens_W[o], er = sens_erev[o];
            r.ac[u] = make_float2(-sg * L2E * SCALE, sg * m * L2E * SCALE + OFF);
            __half2 h = __floats2half2_rn(w * er, w);
            r.wh[u] = __builtin_bit_cast(unsigned, h);
        }
        sensG[g * S_DIM + j] = r;
    }
}

__device__ __forceinline__ float ffract(float x) {
#if __has_builtin(__builtin_amdgcn_fractf)
    return __builtin_amdgcn_fractf(x);
#else
    return x - floorf(x);
#endif
}

// 16-element group: 4 presynaptic i x BT batches
__device__ __forceinline__ void accum_group(
    float4 q0, float4 q1, float4 q2, const float4* vv,
    const char* tblL, float CLHI, float* num, float* den)
{
    float A[4]  = {q0.x, q0.z, q1.x, q1.z};
    float C[4]  = {q0.y, q0.w, q1.y, q1.w};
    unsigned wh[4] = {__float_as_uint(q2.x), __float_as_uint(q2.y),
                      __float_as_uint(q2.z), __float_as_uint(q2.w)};
    #pragma unroll
    for (int u = 0; u < 4; ++u) {
        #pragma unroll
        for (int b = 0; b < BT; ++b) {
            float vb = (u == 0) ? vv[b].x : (u == 1) ? vv[b].y
                     : (u == 2) ? vv[b].z : vv[b].w;
            float f = __builtin_amdgcn_fmed3f(fmaf(A[u], vb, C[u]), 0.0f, CLHI);
            unsigned k = (unsigned)f;           // floor (f >= 0)
            float fr = ffract(f);
            unsigned hv = *(const unsigned*)(tblL + (k << 7));   // k*NREP*4
            float s;
            asm("v_fma_mix_f32 %0, %1, %2, %1 op_sel:[1,0,0] op_sel_hi:[1,0,1]"
                : "=v"(s) : "v"(hv), "v"(fr));  // s = slope*frac + value
            asm("v_fma_mix_f32 %0, %1, %2, %0 op_sel:[0,0,0] op_sel_hi:[1,0,0]"
                : "+v"(num[b]) : "v"(wh[u]), "v"(s));
            asm("v_fma_mix_f32 %0, %1, %2, %0 op_sel:[1,0,0] op_sel_hi:[1,0,0]"
                : "+v"(den[b]) : "v"(wh[u]), "v"(s));
        }
    }
}

__global__ __launch_bounds__(512) void liquid_main(
    const float* __restrict__ inputs,   // [B, I]
    const float* __restrict__ hx,       // [B, S]
    const float* __restrict__ input_w,  // [I]
    const float* __restrict__ input_b,  // [I]
    const Rec* __restrict__ sensG,      // [(I/4)*S]
    const Rec* __restrict__ recG,       // [(S/4)*S]
    const float* __restrict__ vleak,
    const float* __restrict__ gleak,
    const float* __restrict__ cm_t,
    float* __restrict__ out)            // [B, S]
{
    __shared__ unsigned tbl[TBL_N * NREP];          // 128 KB
    __shared__ __align__(16) float vsm[BT][S_DIM];  // 8 KB
    __shared__ __align__(16) float xsm[BT][I_DIM];  // 2 KB

    const int j = threadIdx.x;
    const int b0 = blockIdx.x * BT;

    // table: entry k = (value s(t_k), slope s(t_{k+1})-s(t_k)), t_k = (k-N/2)*hb
    // writes rotated by lane so each write wave hits 32 distinct banks.
    {
        const float hb = (2.0f * T_MAX) / (float)TBL_N;
        for (int k = j; k < TBL_N; k += S_DIM) {
            float t0 = ((float)(k - TBL_N / 2)) * hb;
            float s0 = 1.0f / (1.0f + exp2f(t0));
            float s1 = 1.0f / (1.0f + exp2f(t0 + hb));
            unsigned u = __builtin_bit_cast(unsigned, __floats2half2_rn(s0, s1 - s0));
            #pragma unroll
            for (int r = 0; r < NREP; ++r)
                tbl[k * NREP + ((j + r) & 31)] = u;
        }
    }
    {
        int b = j >> 7, ii = j & 127;
        xsm[b][ii] = inputs[(b0 + b) * I_DIM + ii] * input_w[ii] + input_b[ii];
    }
    #pragma unroll
    for (int b = 0; b < BT; ++b)
        vsm[b][j] = hx[(b0 + b) * S_DIM + j];
    __syncthreads();

    const char* tblL = (const char*)tbl + ((j & 31) << 2);
    const float CLHI = (float)(TBL_N - 1);

    // ---- sensory reduction (once) ----
    float snum[BT], sden[BT];
    #pragma unroll
    for (int b = 0; b < BT; ++b) { snum[b] = 0.f; sden[b] = 0.f; }
    {
        const float4* q = (const float4*)(sensG + j);
        for (int g = 0; g < I_DIM / 4; ++g) {
            float4 q0 = q[0], q1 = q[1], q2 = q[2];
            q += 3 * S_DIM;
            float4 xv[BT];
            #pragma unroll
            for (int b = 0; b < BT; ++b)
                xv[b] = *(const float4*)&xsm[b][g * 4];
            accum_group(q0, q1, q2, xv, tblL, CLHI, snum, sden);
        }
    }

    const float gl = gleak[j], vl = vleak[j], cmj = cm_t[j];
    const float glvl = gl * vl;
    const float cg = cmj + gl;

    // ---- unfolds ----
    for (int it = 0; it < UNFOLDS; ++it) {
        float num[BT], den[BT];
        #pragma unroll
        for (int b = 0; b < BT; ++b) { num[b] = snum[b]; den[b] = sden[b]; }

        const float4* q = (const float4*)(recG + j);
        for (int g = 0; g < S_DIM / 4; ++g) {
            float4 q0 = q[0], q1 = q[1], q2 = q[2];
            q += 3 * S_DIM;
            float4 vv[BT];
            #pragma unroll
            for (int b = 0; b < BT; ++b)
                vv[b] = *(const float4*)&vsm[b][g * 4];
            accum_group(q0, q1, q2, vv, tblL, CLHI, num, den);
        }

        float vnew[BT];
        #pragma unroll
        for (int b = 0; b < BT; ++b) {
            float vold = vsm[b][j];
            vnew[b] = (fmaf(cmj, vold, glvl) + num[b]) / (cg + den[b]);
        }
        __syncthreads();
        #pragma unroll
        for (int b = 0; b < BT; ++b) vsm[b][j] = vnew[b];
        __syncthreads();
    }

    #pragma unroll
    for (int b = 0; b < BT; ++b)
        out[(b0 + b) * S_DIM + j] = vsm[b][j];
}

extern "C" void kernel_launch(void* const* d_in, const int* in_sizes, int n_in,
                              void* d_out, int out_size, void* d_ws, size_t ws_size,
                              hipStream_t stream) {
    const float* inputs   = (const float*)d_in[0];
    const float* hx       = (const float*)d_in[1];
    const float* input_w  = (const float*)d_in[2];
    const float* input_b  = (const float*)d_in[3];
    const float* s_mu     = (const float*)d_in[4];
    const float* s_sigma  = (const float*)d_in[5];
    const float* s_W      = (const float*)d_in[6];
    const float* s_erev   = (const float*)d_in[7];
    const float* mu       = (const float*)d_in[8];
    const float* sigma    = (const float*)d_in[9];
    const float* W        = (const float*)d_in[10];
    const float* erev     = (const float*)d_in[11];
    const float* vleak    = (const float*)d_in[12];
    const float* gleak    = (const float*)d_in[13];
    const float* cm_t     = (const float*)d_in[14];
    float* out = (float*)d_out;

    // ws: recG (S/4)*S recs * 48B = 3.0 MB, then sensG (I/4)*S * 48B = 0.75 MB
    Rec* recG  = (Rec*)d_ws;
    Rec* sensG = (Rec*)((char*)d_ws + (size_t)(S_DIM / 4) * S_DIM * sizeof(Rec));

    int prep_threads = (S_DIM / 4) * S_DIM;   // 65536 covers sensory range too
    prep_kernel<<<(prep_threads + 255) / 256, 256, 0, stream>>>(
        s_mu, s_sigma, s_W, s_erev, mu, sigma, W, erev, recG, sensG);

    liquid_main<<<B_TOT / BT, S_DIM, 0, stream>>>(
        inputs, hx, input_w, input_b, sensG, recG, vleak, gleak, cm_t, out);
}